// Round 5
// baseline (240.280 us; speedup 1.0000x reference)
//
#include <hip/hip_runtime.h>
#include <cstdint>
#include <cstddef>

// ALiBi MHA, MI355X/gfx950. fp16 MFMA (16x16x32) pipeline.
// R5 changes vs R4:
//  - flash: 1D grid with LPT ordering (longest heads first) — kills the
//    straggler tail caused by per-head ALiBi-window work variance.
//  - proj GEMM: V written ROW-MAJOR (coalesced) instead of the 2B-scattered
//    transposed store; new vtrans kernel does the [b,s,h,d]->[b,h,d,s]
//    transpose through LDS with 16B coalesced reads+writes.

typedef unsigned short u16;
typedef __attribute__((ext_vector_type(8))) _Float16 half8;
typedef __attribute__((ext_vector_type(8))) unsigned short u16x8;
typedef __attribute__((ext_vector_type(4))) float f32x4;

#define DEVI static __device__ __forceinline__
#define MFMA16(a, b, c) __builtin_amdgcn_mfma_f32_16x16x32_f16(a, b, c, 0, 0, 0)

DEVI u16 f2h_bits(float f) {
  _Float16 h = (_Float16)f;  // v_cvt_f16_f32, RNE
  union { _Float16 h; u16 u; } v; v.h = h;
  return v.u;
}

// async global->LDS, 16B per lane. LDS dest must be wave-uniform base + lane*16.
DEVI void gl_lds16(const u16* g, u16* l) {
  __builtin_amdgcn_global_load_lds(
      (const __attribute__((address_space(1))) void*)g,
      (__attribute__((address_space(3))) void*)l, 16, 0, 0);
}

// ---------------- cast fp32 -> fp16 bits, 4 elems/thread, z selects tensor ----------------
__global__ __launch_bounds__(256) void cast3_h(const float* __restrict__ in0,
                                               const float* __restrict__ in1,
                                               const float* __restrict__ in2,
                                               u16* __restrict__ o0,
                                               u16* __restrict__ o1,
                                               u16* __restrict__ o2, int n) {
  const float* in = blockIdx.z == 0 ? in0 : (blockIdx.z == 1 ? in1 : in2);
  u16* out = blockIdx.z == 0 ? o0 : (blockIdx.z == 1 ? o1 : o2);
  int i = (blockIdx.x * 256 + threadIdx.x) * 4;
  if (i + 3 < n) {
    const float4 v = *(const float4*)(in + i);
    ushort4 o;
    o.x = f2h_bits(v.x); o.y = f2h_bits(v.y); o.z = f2h_bits(v.z); o.w = f2h_bits(v.w);
    *(ushort4*)(out + i) = o;
  }
}

// ---------------- Wt[n][k] = (f16)W[k][n], 1024x1024, LDS-tiled, z selects W ----------------
__global__ __launch_bounds__(256) void transpose4_h(
    const float* __restrict__ W0, const float* __restrict__ W1,
    const float* __restrict__ W2, const float* __restrict__ W3,
    u16* __restrict__ T0, u16* __restrict__ T1, u16* __restrict__ T2,
    u16* __restrict__ T3) {
  const float* W = blockIdx.z == 0 ? W0 : (blockIdx.z == 1 ? W1 : (blockIdx.z == 2 ? W2 : W3));
  u16* Wt = blockIdx.z == 0 ? T0 : (blockIdx.z == 1 ? T1 : (blockIdx.z == 2 ? T2 : T3));
  __shared__ float tile[32][33];
  const int bx = blockIdx.x * 32;
  const int by = blockIdx.y * 32;
  const int x = threadIdx.x & 31;
  const int y0 = threadIdx.x >> 5;  // 0..7
#pragma unroll
  for (int i = y0; i < 32; i += 8)
    tile[i][x] = W[(size_t)(by + i) * 1024 + bx + x];
  __syncthreads();
#pragma unroll
  for (int i = y0; i < 32; i += 8)
    Wt[(size_t)(bx + i) * 1024 + by + x] = f2h_bits(tile[x][i]);
}

// ---- Vt[(b*16+h)*64+d][s] = Vp[b*2048+s][h*64+d], via 64x64 LDS tile ----
// grid (32 s-tiles, 32 bh). Reads: 16B coalesced rows. Writes: 16B contiguous in s.
__global__ __launch_bounds__(256) void vtrans(const u16* __restrict__ Vp,
                                              u16* __restrict__ Vt) {
  __shared__ u16 tile[64][72];  // +8 pad breaks transpose-read bank alignment
  const int t = threadIdx.x;
  const int s0 = blockIdx.x * 64;
  const int bh = blockIdx.y;            // b*16 + h
  const int b = bh >> 4, h = bh & 15;
#pragma unroll
  for (int it = 0; it < 2; ++it) {
    const int ci = it * 256 + t;
    const int srow = ci >> 3, cc = (ci & 7) << 3;
    const u16x8 v = *(const u16x8*)(Vp + (size_t)(b * 2048 + s0 + srow) * 1024 + h * 64 + cc);
    *(u16x8*)(&tile[srow][cc]) = v;
  }
  __syncthreads();
#pragma unroll
  for (int it = 0; it < 2; ++it) {
    const int ci = it * 256 + t;
    const int drow = ci >> 3, cc = (ci & 7) << 3;
    u16x8 o;
#pragma unroll
    for (int j = 0; j < 8; ++j) o[j] = tile[cc + j][drow];
    *(u16x8*)(Vt + ((size_t)bh * 64 + drow) * 2048 + s0 + cc) = o;
  }
}

// ---------------- GEMM body: C[4096x1024] = A[4096x1024] x Bt[1024x1024]^T ----------------
// 32-elem rows in LDS = 4 chunks of 8; staging-side chunk XOR breaks the 8-way
// frag-read conflict of the 64B row stride. mode 0: fp32 out; mode 1: fp16 out.
DEVI void gemm_body(const u16* __restrict__ A, const u16* __restrict__ Bt,
                    void* __restrict__ Cout, int mode, u16* As, u16* Bs) {
  constexpr int K = 1024, N = 1024;
  const int t = threadIdx.x;
  const int lane = t & 63;
  const int quad = lane >> 4;
  const int l16 = lane & 15;
  const int wid = t >> 6;
  const int mBase = blockIdx.y * 128;
  const int nBase = blockIdx.x * 128;
  const int wM = (wid >> 1) * 64;
  const int wN = (wid & 1) * 64;
  const int aswz = (quad ^ ((l16 >> 1) & 3)) << 3;  // frag-read physical col

  f32x4 acc[4][4];
#pragma unroll
  for (int i = 0; i < 4; ++i)
#pragma unroll
    for (int j = 0; j < 4; ++j) acc[i][j] = (f32x4){0.f, 0.f, 0.f, 0.f};

  for (int kt = 0; kt < K / 32; ++kt) {
    const int kB = kt * 32;
    __syncthreads();  // protect LDS reuse from previous iteration's reads
#pragma unroll
    for (int i = 0; i < 2; ++i) {  // 128x32 f16 tile = 8KB = 512 16B-chunks / 256 thr
      const int ci = i * 256 + t;
      const int row = ci >> 2;                              // 4 chunks per 32-elem row
      const int col = (((ci & 3) ^ ((ci >> 3) & 3)) << 3);  // staging-side swizzle
      gl_lds16(A + (size_t)(mBase + row) * K + kB + col, As + ci * 8);
      gl_lds16(Bt + (size_t)(nBase + row) * K + kB + col, Bs + ci * 8);
    }
    __syncthreads();  // barrier drains vmcnt

    half8 a[4], b[4];
#pragma unroll
    for (int mi = 0; mi < 4; ++mi)
      a[mi] = *(const half8*)(As + (wM + mi * 16 + l16) * 32 + aswz);
#pragma unroll
    for (int ni = 0; ni < 4; ++ni)
      b[ni] = *(const half8*)(Bs + (wN + ni * 16 + l16) * 32 + aswz);
#pragma unroll
    for (int mi = 0; mi < 4; ++mi)
#pragma unroll
      for (int ni = 0; ni < 4; ++ni)
        acc[mi][ni] = MFMA16(a[mi], b[ni], acc[mi][ni]);
  }

  // epilogue. C/D layout: row = quad*4 + reg, col = lane&15 (m89/m91-verified)
#pragma unroll
  for (int mi = 0; mi < 4; ++mi) {
#pragma unroll
    for (int ni = 0; ni < 4; ++ni) {
#pragma unroll
      for (int r = 0; r < 4; ++r) {
        const int m = mBase + wM + mi * 16 + quad * 4 + r;
        const int n = nBase + wN + ni * 16 + l16;
        const float v = acc[mi][ni][r];
        if (mode == 0) {
          ((float*)Cout)[(size_t)m * N + n] = v;
        } else {
          ((u16*)Cout)[(size_t)m * N + n] = f2h_bits(v);
        }
      }
    }
  }
}

__global__ __launch_bounds__(256) void proj_qkv(
    const u16* __restrict__ qb, const u16* __restrict__ kb, const u16* __restrict__ vb,
    const u16* __restrict__ Wqt, const u16* __restrict__ Wkt, const u16* __restrict__ Wvt,
    u16* __restrict__ Qp, u16* __restrict__ Kp, u16* __restrict__ Vp) {
  __shared__ u16 As[128 * 32];
  __shared__ u16 Bs[128 * 32];
  const int z = blockIdx.z;
  const u16* A = z == 0 ? qb : (z == 1 ? kb : vb);
  const u16* Bt = z == 0 ? Wqt : (z == 1 ? Wkt : Wvt);
  void* C = z == 0 ? (void*)Qp : (z == 1 ? (void*)Kp : (void*)Vp);
  gemm_body(A, Bt, C, 1, As, Bs);
}

__global__ __launch_bounds__(256) void gemm_out(const u16* __restrict__ Ao,
                                                const u16* __restrict__ Wot,
                                                float* __restrict__ out) {
  __shared__ u16 As[128 * 32];
  __shared__ u16 Bs[128 * 32];
  gemm_body(Ao, Wot, out, 0, As, Bs);
}

// ---------------- flash attention + ALiBi, no-max exp2 softmax ----------------
// 1D grid 1024 = LPT order (h=15 first: longest ALiBi window -> most k-tiles).
// 128 thr = 2 waves x 32 q-rows, K-tile 64. Qs/Ks/Vs chunk-swizzled on the
// global side of staging (2-way banks). ALiBi skip: tile dropped when
// sl2*dist > 30 (neglected mass < 2^-15 of l).
__global__ __launch_bounds__(128, 2) void flash_alibi(
    const u16* __restrict__ Qg, const u16* __restrict__ Kg,
    const u16* __restrict__ Vtg, u16* __restrict__ Og) {
  constexpr int S = 2048, Dm = 1024, HD = 64;
  __shared__ u16 Qs[64 * 64];   // 8 KB
  __shared__ u16 Ks[64 * 64];   // 8 KB
  __shared__ u16 Vs[64 * 64];   // 8 KB  Vs[d][k]
  __shared__ u16 Ps[64 * 64];   // 8 KB  col-swizzled
  const int t = threadIdx.x, lane = t & 63, wid = t >> 6;  // wid 0..1
  const int quad = lane >> 4, l16 = lane & 15;
  const int idx = blockIdx.x;
  const int h = 15 - (idx >> 6);       // LPT: longest heads dispatched first
  const int qt = (idx >> 1) & 31;
  const int b = idx & 1;
  const int qBase = qt * 64;
  const size_t qRow0 = (size_t)b * S + qBase;
  const float sl2 = __builtin_amdgcn_exp2f(-0.5f * (float)(h + 1)) * 1.44269504f;
  const float sc2 = 0.125f * 1.44269504f;  // (1/sqrt(64))*log2(e)
  const int Di = (int)(30.0f / sl2);
  const int ktLo = max(0, (qBase - Di) >> 6);
  const int ktHi = min(31, (qBase + 63 + Di) >> 6);
  const int cswz = ((l16 & 7) << 3);  // frag-read chunk xor (x8 elems)

  // stage Q tile once: 64 rows x 8 chunks = 512 chunks / 128 thr
#pragma unroll
  for (int i = 0; i < 4; ++i) {
    const int ci = i * 128 + t;
    const int row = ci >> 3, col = (((ci & 7) ^ (row & 7)) << 3);
    gl_lds16(Qg + (qRow0 + row) * Dm + h * HD + col, Qs + ci * 8);
  }

  // ALiBi row bias (constant over kt): bi[m][r] = sl2 * global_q_row
  float bi[2][4];
#pragma unroll
  for (int m = 0; m < 2; ++m)
#pragma unroll
    for (int r = 0; r < 4; ++r)
      bi[m][r] = sl2 * (float)(qBase + wid * 32 + m * 16 + quad * 4 + r);

  f32x4 acc_o[2][4];
#pragma unroll
  for (int m = 0; m < 2; ++m)
#pragma unroll
    for (int nd = 0; nd < 4; ++nd) acc_o[m][nd] = (f32x4){0.f, 0.f, 0.f, 0.f};
  float lrow[2][4] = {{0.f, 0.f, 0.f, 0.f}, {0.f, 0.f, 0.f, 0.f}};

  const int pRowBase = wid * 32;  // this wave's private 32-row P region

  for (int kt = ktLo; kt <= ktHi; ++kt) {
    const int kB = kt * 64;
    __syncthreads();  // prev-iter Ks/Vs reads done (also: Q staging drained, iter 0)
#pragma unroll
    for (int i = 0; i < 4; ++i) {  // K tile 64x64 and V tile: 512 chunks each / 128 thr
      const int ci = i * 128 + t;
      const int row = ci >> 3, col = (((ci & 7) ^ (row & 7)) << 3);
      gl_lds16(Kg + ((size_t)b * S + kB + row) * Dm + h * HD + col, Ks + ci * 8);
      gl_lds16(Vtg + ((size_t)(b * 16 + h) * HD + row) * S + kB + col, Vs + ci * 8);
    }
    __syncthreads();

    // S = Q K^T : per wave 32q x 64k
    f32x4 s[2][4];
#pragma unroll
    for (int m = 0; m < 2; ++m)
#pragma unroll
      for (int ni = 0; ni < 4; ++ni) s[m][ni] = (f32x4){0.f, 0.f, 0.f, 0.f};
#pragma unroll
    for (int ks = 0; ks < 2; ++ks) {
      const int ck = ((ks * 4 + quad) << 3) ^ cswz;
      const half8 a0 = *(const half8*)(Qs + (wid * 32 + l16) * HD + ck);
      const half8 a1 = *(const half8*)(Qs + (wid * 32 + 16 + l16) * HD + ck);
#pragma unroll
      for (int ni = 0; ni < 4; ++ni) {
        const half8 bk = *(const half8*)(Ks + (ni * 16 + l16) * HD + ck);
        s[0][ni] = MFMA16(a0, bk, s[0][ni]);
        s[1][ni] = MFMA16(a1, bk, s[1][ni]);
      }
    }

    // p = exp2(s*sc2 - |bi - bj|); per-lane l partials; write swizzled P
    float bj[4];
#pragma unroll
    for (int ni = 0; ni < 4; ++ni) bj[ni] = sl2 * (float)(kB + ni * 16 + l16);
#pragma unroll
    for (int m = 0; m < 2; ++m) {
#pragma unroll
      for (int r = 0; r < 4; ++r) {
        float rs = 0.f;
        const int prow = (pRowBase + m * 16 + quad * 4 + r) * 64;
#pragma unroll
        for (int ni = 0; ni < 4; ++ni) {
          const float d = fabsf(bi[m][r] - bj[ni]);
          const float p = __builtin_amdgcn_exp2f(s[m][ni][r] * sc2 - d);
          rs += p;
          Ps[prow + ((ni * 16 + l16) ^ (quad << 4))] = f2h_bits(p);
        }
        lrow[m][r] += rs;
      }
    }
    // P region is per-wave: wave-local LDS drain is sufficient (no block barrier)
    __asm__ volatile("s_waitcnt lgkmcnt(0)" ::: "memory");

    // O += P V : P A-frags (swizzled, 16B-contiguous), V B-frags
#pragma unroll
    for (int ks = 0; ks < 2; ++ks) {
      const int pk = (ks * 32 + quad * 8) ^ ((l16 & 12) << 2);
      const int ck = ((ks * 4 + quad) << 3) ^ cswz;
      const half8 aP0 = *(const half8*)(Ps + (pRowBase + l16) * 64 + pk);
      const half8 aP1 = *(const half8*)(Ps + (pRowBase + 16 + l16) * 64 + pk);
#pragma unroll
      for (int nd = 0; nd < 4; ++nd) {
        const half8 bv = *(const half8*)(Vs + (nd * 16 + l16) * HD + ck);
        acc_o[0][nd] = MFMA16(aP0, bv, acc_o[0][nd]);
        acc_o[1][nd] = MFMA16(aP1, bv, acc_o[1][nd]);
      }
    }
  }

  // epilogue: reduce l across the 16 lanes sharing each row, O /= l, write f16
#pragma unroll
  for (int m = 0; m < 2; ++m) {
#pragma unroll
    for (int r = 0; r < 4; ++r) {
      float l = lrow[m][r];
      l += __shfl_xor(l, 1);
      l += __shfl_xor(l, 2);
      l += __shfl_xor(l, 4);
      l += __shfl_xor(l, 8);
      const float inv = 1.f / l;
      const int rloc = wid * 32 + m * 16 + quad * 4 + r;
#pragma unroll
      for (int nd = 0; nd < 4; ++nd)
        Og[(qRow0 + rloc) * Dm + h * HD + nd * 16 + l16] = f2h_bits(acc_o[m][nd][r] * inv);
    }
  }
}

extern "C" void kernel_launch(void* const* d_in, const int* in_sizes, int n_in,
                              void* d_out, int out_size, void* d_ws, size_t ws_size,
                              hipStream_t stream) {
  const float* q  = (const float*)d_in[0];
  const float* k  = (const float*)d_in[1];
  const float* v  = (const float*)d_in[2];
  const float* Wq = (const float*)d_in[3];
  const float* Wk = (const float*)d_in[4];
  const float* Wv = (const float*)d_in[5];
  const float* Wo = (const float*)d_in[6];
  char* ws = (char*)d_ws;
  const size_t MB = 1ull << 20;
  // workspace map (64 MB total)
  u16* qb  = (u16*)(ws + 0 * MB);    // 8 MB  q fp16
  u16* kb  = (u16*)(ws + 8 * MB);    // 8 MB
  u16* vb  = (u16*)(ws + 16 * MB);   // 8 MB  (reused as Vt after proj consumes it)
  u16* Wqt = (u16*)(ws + 24 * MB);   // 2 MB  W^T fp16
  u16* Wkt = (u16*)(ws + 26 * MB);
  u16* Wvt = (u16*)(ws + 28 * MB);
  u16* Wot = (u16*)(ws + 30 * MB);
  u16* Qp  = (u16*)(ws + 32 * MB);   // 8 MB  Q proj [4096][1024]
  u16* Kp  = (u16*)(ws + 40 * MB);   // 8 MB
  u16* Vp  = (u16*)(ws + 48 * MB);   // 8 MB  V proj row-major [4096][1024]
  u16* Ao  = (u16*)(ws + 56 * MB);   // 8 MB  attention out [4096][1024]
  u16* Vt  = vb;                     // Vt[b][h][64][2048] overwrites vb (safe: proj done)

  const int n = 2 * 2048 * 1024;
  cast3_h<<<dim3(n / 1024, 1, 3), 256, 0, stream>>>(q, k, v, qb, kb, vb, n);
  transpose4_h<<<dim3(32, 32, 4), 256, 0, stream>>>(Wq, Wk, Wv, Wo, Wqt, Wkt, Wvt, Wot);
  proj_qkv<<<dim3(8, 32, 3), 256, 0, stream>>>(qb, kb, vb, Wqt, Wkt, Wvt, Qp, Kp, Vp);
  vtrans<<<dim3(32, 32), 256, 0, stream>>>(Vp, Vt);
  flash_alibi<<<1024, 128, 0, stream>>>(Qp, Kp, Vt, Ao);
  gemm_out<<<dim3(8, 32), 256, 0, stream>>>(Ao, Wot, (float*)d_out);
}